// Round 18
// baseline (362.516 us; speedup 1.0000x reference)
//
#include <hip/hip_runtime.h>
#include <hip/hip_bf16.h>

// MoE SwiGLU: H=2048, I=1408, E=8, TOPK=2, T=4096 tokens (8192 pairs).
// R18 = R17 with ONE change in gemm2's K-loop: counted s_waitcnt vmcnt(8) +
// raw s_barrier (inline asm) instead of __syncthreads. The vmcnt(8) waits only
// for the tile staged ONE PHASE AGO (8 newer loads stay in flight across the
// barrier) -- the T4 mechanism __syncthreads cannot express (it always drains
// vmcnt to 0). lgkmcnt(0) before the trailing barrier closes the in-flight
// ds_read vs next-stage-overwrite race. gemm1 untouched as control.

typedef __bf16 bf16;
typedef bf16 bf16x8 __attribute__((ext_vector_type(8)));
typedef float f32x4 __attribute__((ext_vector_type(4)));

constexpr int Hdim = 2048;
constexpr int Idim = 1408;
constexpr int NE = 8;
constexpr int TOPK = 2;
constexpr int NT = 4096;      // tokens
constexpr int NPAIR = 8192;   // T * TOPK
constexpr int BK = 64;

#define GLOAD16(G, L) __builtin_amdgcn_global_load_lds(                    \
    (const __attribute__((address_space(1))) void*)(G),                    \
    (__attribute__((address_space(3))) void*)(L), 16, 0, 0)

// counted-vmcnt barrier pair (T4): tile staged one phase ago is resident
#define WAITBAR_V8() asm volatile("s_waitcnt vmcnt(8)\n\ts_barrier" ::: "memory")
#define WAITBAR_V0() asm volatile("s_waitcnt vmcnt(0)\n\ts_barrier" ::: "memory")
// end-of-phase barrier: all this wave's ds_reads complete, then sync
#define BARRIER_LG0() asm volatile("s_waitcnt lgkmcnt(0)\n\ts_barrier" ::: "memory")

// ---------------- f32 -> bf16 convert (streaming) ----------------

__global__ void k_cvt(const float* __restrict__ src, bf16* __restrict__ dst, int n8) {
    int i = blockIdx.x * 256 + threadIdx.x;
    if (i >= n8) return;
    f32x4 a = *reinterpret_cast<const f32x4*>(src + (size_t)i * 8);
    f32x4 b = *reinterpret_cast<const f32x4*>(src + (size_t)i * 8 + 4);
    bf16x8 v;
#pragma unroll
    for (int j = 0; j < 4; j++) { v[j] = (bf16)a[j]; v[4 + j] = (bf16)b[j]; }
    *reinterpret_cast<bf16x8*>(dst + (size_t)i * 8) = v;
}

// ---------------- binning (deterministic) ----------------

__global__ void k_bin1(const int* __restrict__ eidx, int* __restrict__ chunkhist) {
    __shared__ int h[NE];
    int t = threadIdx.x;
    if (t < NE) h[t] = 0;
    __syncthreads();
    int p = blockIdx.x * 256 + t;
    atomicAdd(&h[eidx[p]], 1);
    __syncthreads();
    if (t < NE) chunkhist[blockIdx.x * NE + t] = h[t];
}

__global__ void k_bin2(int* __restrict__ meta, const int* __restrict__ chunkhist,
                       int* __restrict__ chunkbase) {
    if (threadIdx.x == 0) {
        int counts[NE];
        for (int e = 0; e < NE; e++) counts[e] = 0;
        for (int b = 0; b < 32; b++)
            for (int e = 0; e < NE; e++) {
                chunkbase[b * NE + e] = counts[e];
                counts[e] += chunkhist[b * NE + e];
            }
        int acc = 0;
        for (int e = 0; e < NE; e++) {
            meta[e] = counts[e];      // counts
            meta[8 + e] = acc;        // exclusive offsets
            acc += counts[e];
        }
    }
}

__global__ void k_bin3(const int* __restrict__ eidx, const float* __restrict__ wts,
                       const int* __restrict__ meta, const int* __restrict__ chunkbase,
                       int* __restrict__ token_id, float* __restrict__ weightv) {
    __shared__ int earr[256];
    int t = threadIdx.x;
    int p = blockIdx.x * 256 + t;
    int e = eidx[p];
    earr[t] = e;
    __syncthreads();
    int rank = 0;
    for (int q = 0; q < t; q++) rank += (earr[q] == e) ? 1 : 0;
    int pos = meta[8 + e] + chunkbase[blockIdx.x * NE + e] + rank;
    token_id[pos] = p / TOPK;
    weightv[pos] = wts[p];
}

// ---------------- GEMM1: gu = X_e * w13[e]^T, fused SwiGLU (R7/R14 verbatim) ----------------
// Flat grid 1408 = 16 m-slots x 11 y-tiles x 8 experts. XCD-chunk swizzle:
// work = (flat%8)*176 + flat/8; grp = work>>4 in [11k, 11k+11) on XCD k.

__global__ __launch_bounds__(256, 2) void k_gemm1(
    const bf16* __restrict__ xb, const bf16* __restrict__ w13b,
    const int* __restrict__ meta, bf16* __restrict__ hact) {
    const int flat = blockIdx.x;
    const int work = (flat & 7) * 176 + (flat >> 3);
    const int mslot = work & 15;
    const int grp = work >> 4;        // [0,88)
    const int e = grp / 11;
    const int ytile = grp - e * 11;

    const int n_e = meta[e];
    const int m0 = mslot * 128;
    if (m0 >= n_e) return;
    const int base = meta[8 + e];
    const int* toks = (const int*)(meta + 64) + base;
    const bf16* wg = w13b + (size_t)e * (2 * Idim) * Hdim + (size_t)(ytile * 128) * Hdim;
    const bf16* wu = wg + (size_t)Idim * Hdim;

    __shared__ bf16 As[128 * 64];
    __shared__ bf16 Bg[128 * 64];
    __shared__ bf16 Bu[128 * 64];

    const int tid = threadIdx.x;
    const int lane = tid & 63;
    const int wid = tid >> 6;
    const int wr = wid >> 1, wc = wid & 1;
    const int l16 = lane & 15, lq = lane >> 4;

    // staging: 1024 slots of 16B per tile, 4 rounds x 256 threads.
    // LDS dest LINEAR; global source pre-swizzled: LDS seg s of row r holds
    // global seg s^(r&7).
    const bf16* gA[4];
    const bf16* gG[4];
    const bf16* gU[4];
    int lo[4];
#pragma unroll
    for (int r = 0; r < 4; r++) {
        int sid = r * 256 + tid;
        int row = sid >> 3, seg = sid & 7;
        int ss = seg ^ (row & 7);
        lo[r] = (r * 256 + (tid & ~63)) * 16;   // wave-uniform LDS byte base
        int rr = m0 + row;
        if (rr >= n_e) rr = n_e - 1;            // clamp keeps reads in-bounds
        gA[r] = xb + (size_t)toks[rr] * Hdim + ss * 8;
        gG[r] = wg + (size_t)row * Hdim + ss * 8;
        gU[r] = wu + (size_t)row * Hdim + ss * 8;
    }

    f32x4 accg[4][4], accu[4][4];
#pragma unroll
    for (int m = 0; m < 4; m++)
#pragma unroll
        for (int n = 0; n < 4; n++) {
            accg[m][n] = f32x4{0.f, 0.f, 0.f, 0.f};
            accu[m][n] = f32x4{0.f, 0.f, 0.f, 0.f};
        }

    for (int k0 = 0; k0 < Hdim; k0 += BK) {
        __syncthreads();
#pragma unroll
        for (int r = 0; r < 4; r++) {
            GLOAD16(gA[r] + k0, (char*)As + lo[r]);
            GLOAD16(gG[r] + k0, (char*)Bg + lo[r]);
            GLOAD16(gU[r] + k0, (char*)Bu + lo[r]);
        }
        __syncthreads();
#pragma unroll
        for (int kk = 0; kk < 2; ++kk) {
            bf16x8 af[4], bgf[4], buf_[4];
#pragma unroll
            for (int m = 0; m < 4; m++) {
                int row = wr * 64 + m * 16 + l16;
                int s = (kk * 4 + lq) ^ (row & 7);
                af[m] = *reinterpret_cast<const bf16x8*>(&As[row * 64 + s * 8]);
            }
#pragma unroll
            for (int n = 0; n < 4; n++) {
                int row = wc * 64 + n * 16 + l16;
                int s = (kk * 4 + lq) ^ (row & 7);
                bgf[n] = *reinterpret_cast<const bf16x8*>(&Bg[row * 64 + s * 8]);
                buf_[n] = *reinterpret_cast<const bf16x8*>(&Bu[row * 64 + s * 8]);
            }
#pragma unroll
            for (int m = 0; m < 4; m++)
#pragma unroll
                for (int n = 0; n < 4; n++) {
                    accg[m][n] = __builtin_amdgcn_mfma_f32_16x16x32_bf16(af[m], bgf[n], accg[m][n], 0, 0, 0);
                    accu[m][n] = __builtin_amdgcn_mfma_f32_16x16x32_bf16(af[m], buf_[n], accu[m][n], 0, 0, 0);
                }
        }
    }

    // epilogue: silu(g)*u -> hact. C layout: col=lane&15, row=(lane>>4)*4+reg
    const int colbase = ytile * 128 + wc * 64;
#pragma unroll
    for (int m = 0; m < 4; m++) {
        int lr0 = m0 + wr * 64 + m * 16 + lq * 4;
#pragma unroll
        for (int j = 0; j < 4; j++) {
            int lr = lr0 + j;
            if (lr < n_e) {
                size_t rowoff = (size_t)(base + lr) * Idim;
#pragma unroll
                for (int n = 0; n < 4; n++) {
                    float g = accg[m][n][j], u = accu[m][n][j];
                    float v = (g / (1.f + __expf(-g))) * u;
                    hact[rowoff + colbase + n * 16 + l16] = (bf16)v;
                }
            }
        }
    }
}

// ---------------- GEMM2: y = hact * down_proj[e]^T, weighted scatter-add ----------------
// 128x128 tile, BK=64. Named dbuf A0/B0/A1/B1 (4 x 16KB). Counted-vmcnt
// 2-phase (T4): per phase {STAGE(next); vmcnt(8)+bar; ds_read+MFMA(cur);
// lgkmcnt(0)+bar}. vmcnt(8) waits only for the tile staged one phase ago;
// the 8 loads just issued stay in flight across the barrier.
// Flat grid 2048 = 16 m-slots x 16 y-tiles x 8 experts; XCD-chunk swizzle.

__global__ __launch_bounds__(256, 2) void k_gemm2(
    const bf16* __restrict__ hact, const bf16* __restrict__ dpb,
    const int* __restrict__ meta, const float* __restrict__ weightv,
    float* __restrict__ out) {
    const int flat = blockIdx.x;
    const int work = (flat & 7) * 256 + (flat >> 3);
    const int mslot = work & 15;
    const int grp = work >> 4;        // [0,128)
    const int e = grp >> 4;
    const int ytile = grp & 15;

    const int n_e = meta[e];
    const int m0 = mslot * 128;
    if (m0 >= n_e) return;
    const int base = meta[8 + e];
    const int* toks = (const int*)(meta + 64) + base;
    const bf16* wb = dpb + (size_t)e * Hdim * Idim + (size_t)(ytile * 128) * Idim;

    // four distinct objects -> static disjointness for alias analysis
    __shared__ bf16 A0[128 * 64];
    __shared__ bf16 B0[128 * 64];
    __shared__ bf16 A1[128 * 64];
    __shared__ bf16 B1[128 * 64];

    const int tid = threadIdx.x;
    const int lane = tid & 63;
    const int wid = tid >> 6;
    const int wr = wid >> 1, wc = wid & 1;
    const int l16 = lane & 15, lq = lane >> 4;

    const bf16* gA[4];
    const bf16* gB[4];
    int lo[4];
#pragma unroll
    for (int r = 0; r < 4; r++) {
        int sid = r * 256 + tid;
        int row = sid >> 3, seg = sid & 7;
        int ss = seg ^ (row & 7);
        lo[r] = (r * 256 + (tid & ~63)) * 16;
        int rr = m0 + row;
        if (rr >= n_e) rr = n_e - 1;
        gA[r] = hact + (size_t)(base + rr) * Idim + ss * 8;
        gB[r] = wb + (size_t)row * Idim + ss * 8;
    }

    f32x4 acc[4][4];
#pragma unroll
    for (int m = 0; m < 4; m++)
#pragma unroll
        for (int n = 0; n < 4; n++) acc[m][n] = f32x4{0.f, 0.f, 0.f, 0.f};

#define STG2(AB, BB, K0)                                                    \
    {                                                                       \
        _Pragma("unroll")                                                   \
        for (int r = 0; r < 4; r++) {                                       \
            GLOAD16(gA[r] + (K0), (char*)(AB) + lo[r]);                     \
            GLOAD16(gB[r] + (K0), (char*)(BB) + lo[r]);                     \
        }                                                                   \
    }

#define CMP2(AB, BB)                                                        \
    {                                                                       \
        _Pragma("unroll")                                                   \
        for (int kk = 0; kk < 2; ++kk) {                                    \
            bf16x8 af[4], bf_[4];                                           \
            _Pragma("unroll")                                               \
            for (int m = 0; m < 4; m++) {                                   \
                int row = wr * 64 + m * 16 + l16;                           \
                int s = (kk * 4 + lq) ^ (row & 7);                          \
                af[m] = *reinterpret_cast<const bf16x8*>(&(AB)[row * 64 + s * 8]); \
            }                                                               \
            _Pragma("unroll")                                               \
            for (int n = 0; n < 4; n++) {                                   \
                int row = wc * 64 + n * 16 + l16;                           \
                int s = (kk * 4 + lq) ^ (row & 7);                          \
                bf_[n] = *reinterpret_cast<const bf16x8*>(&(BB)[row * 64 + s * 8]); \
            }                                                               \
            _Pragma("unroll")                                               \
            for (int m = 0; m < 4; m++)                                     \
                _Pragma("unroll")                                           \
                for (int n = 0; n < 4; n++)                                 \
                    acc[m][n] = __builtin_amdgcn_mfma_f32_16x16x32_bf16(af[m], bf_[n], acc[m][n], 0, 0, 0); \
        }                                                                   \
    }

    // prologue: tile 0 -> buf0 (8 loads in flight)
    STG2(A0, B0, 0);
    // steady state: 22 K-steps; loop covers tiles 0..19, epilogue 20,21.
    // Invariant at each WAITBAR_V8: 16 loads outstanding -> wait to 8 ->
    // the OLDER tile's 8 loads (issued one phase ago) are resident.
    for (int t = 0; t < 20; t += 2) {
        STG2(A1, B1, (t + 1) * BK);
        WAITBAR_V8();                  // tile t resident; tile t+1 in flight
        CMP2(A0, B0);
        BARRIER_LG0();                 // all waves' reads of A0/B0 done
        STG2(A0, B0, (t + 2) * BK);
        WAITBAR_V8();                  // tile t+1 resident; tile t+2 in flight
        CMP2(A1, B1);
        BARRIER_LG0();
    }
    STG2(A1, B1, 21 * BK);
    WAITBAR_V8();                      // tile 20 resident
    CMP2(A0, B0);
    BARRIER_LG0();
    WAITBAR_V0();                      // tile 21 resident
    CMP2(A1, B1);

    const int colbase = ytile * 128 + wc * 64;
#pragma unroll
    for (int m = 0; m < 4; m++) {
        int lr0 = m0 + wr * 64 + m * 16 + lq * 4;
#pragma unroll
        for (int j = 0; j < 4; j++) {
            int lr = lr0 + j;
            if (lr < n_e) {
                int tok = toks[lr];
                float w = weightv[base + lr];
#pragma unroll
                for (int n = 0; n < 4; n++) {
                    float v = acc[m][n][j] * w;
                    unsafeAtomicAdd(&out[(size_t)tok * Hdim + colbase + n * 16 + l16], v);
                }
            }
        }
    }
#undef STG2
#undef CMP2
}

// ---------------- launch ----------------

extern "C" void kernel_launch(void* const* d_in, const int* in_sizes, int n_in,
                              void* d_out, int out_size, void* d_ws, size_t ws_size,
                              hipStream_t stream) {
    const float* x = (const float*)d_in[0];
    const int* eidx = (const int*)d_in[1];
    const float* ewts = (const float*)d_in[2];
    const float* w13 = (const float*)d_in[3];
    const float* dproj = (const float*)d_in[4];
    float* out = (float*)d_out;

    // ws layout (bytes): ints block [0, 67840), then bf16 buffers (16B-aligned)
    char* ws = (char*)d_ws;
    int* meta = (int*)ws;                       // [0..7] counts, [8..15] offsets
    int* token_id = meta + 64;                  // [NPAIR]
    float* weightv = (float*)(meta + 64 + NPAIR);
    int* chunkhist = meta + 64 + 2 * NPAIR;     // [32*NE]
    int* chunkbase = chunkhist + 256;           // [32*NE]
    bf16* xb = (bf16*)(ws + 67840);             // [NT][Hdim]
    bf16* w13b = xb + (size_t)NT * Hdim;        // [NE][2*Idim][Hdim]
    bf16* dpb = w13b + (size_t)NE * 2 * Idim * Hdim;  // [NE][Hdim][Idim]
    bf16* hact = dpb + (size_t)NE * Hdim * Idim;      // [NPAIR][Idim]

    hipMemsetAsync(d_out, 0, (size_t)out_size * sizeof(float), stream);

    const int nx8 = NT * Hdim / 8;                    // 1048576
    const int nw8 = NE * 2 * Idim * Hdim / 8;         // 5767168
    const int nd8 = NE * Hdim * Idim / 8;             // 2883584
    k_cvt<<<(nx8 + 255) / 256, 256, 0, stream>>>(x, xb, nx8);
    k_cvt<<<(nw8 + 255) / 256, 256, 0, stream>>>(w13, w13b, nw8);
    k_cvt<<<(nd8 + 255) / 256, 256, 0, stream>>>(dproj, dpb, nd8);

    k_bin1<<<32, 256, 0, stream>>>(eidx, chunkhist);
    k_bin2<<<1, 64, 0, stream>>>(meta, chunkhist, chunkbase);
    k_bin3<<<32, 256, 0, stream>>>(eidx, ewts, meta, chunkbase, token_id, weightv);

    k_gemm1<<<1408, 256, 0, stream>>>(xb, w13b, meta, hact);
    k_gemm2<<<2048, 256, 0, stream>>>(hact, dpb, meta, weightv, out);
}

// Round 19
// 349.407 us; speedup vs baseline: 1.0375x; 1.0375x over previous
//
#include <hip/hip_runtime.h>
#include <hip/hip_bf16.h>

// MoE SwiGLU: H=2048, I=1408, E=8, TOPK=2, T=4096 tokens (8192 pairs).
// R19 = R14 exact (measured optimum of the 2-barrier family: 351.8us) with
// the 3 cvt launches merged into 1 kernel (saves 2 launch gaps).
// History: R15/R17 (named-dbuf syncthreads) and R18 (counted vmcnt(8) + raw
// barriers) were both CORRECT but neutral-to-worse on gemm2 -- reproducing the
// guide's regime-gate: T3/T4 pay only inside the full 8-phase interleave.

typedef __bf16 bf16;
typedef bf16 bf16x8 __attribute__((ext_vector_type(8)));
typedef float f32x4 __attribute__((ext_vector_type(4)));

constexpr int Hdim = 2048;
constexpr int Idim = 1408;
constexpr int NE = 8;
constexpr int TOPK = 2;
constexpr int NT = 4096;      // tokens
constexpr int NPAIR = 8192;   // T * TOPK
constexpr int BK = 64;
constexpr int NX8 = NT * Hdim / 8;             // 1048576
constexpr int NW8 = NE * 2 * Idim * Hdim / 8;  // 5767168
constexpr int ND8 = NE * Hdim * Idim / 8;      // 2883584

#define GLOAD16(G, L) __builtin_amdgcn_global_load_lds(                    \
    (const __attribute__((address_space(1))) void*)(G),                    \
    (__attribute__((address_space(3))) void*)(L), 16, 0, 0)

// ---------------- f32 -> bf16 convert (all three buffers, one launch) ----------------

__global__ void k_cvt3(const float* __restrict__ x, bf16* __restrict__ xb,
                       const float* __restrict__ w13, bf16* __restrict__ w13b,
                       const float* __restrict__ dp, bf16* __restrict__ dpb) {
    int i = blockIdx.x * 256 + threadIdx.x;
    const float* s;
    bf16* d;
    int off;
    if (i < NX8) { s = x; d = xb; off = i; }
    else if (i < NX8 + NW8) { s = w13; d = w13b; off = i - NX8; }
    else if (i < NX8 + NW8 + ND8) { s = dp; d = dpb; off = i - NX8 - NW8; }
    else return;
    f32x4 a = *reinterpret_cast<const f32x4*>(s + (size_t)off * 8);
    f32x4 b = *reinterpret_cast<const f32x4*>(s + (size_t)off * 8 + 4);
    bf16x8 v;
#pragma unroll
    for (int j = 0; j < 4; j++) { v[j] = (bf16)a[j]; v[4 + j] = (bf16)b[j]; }
    *reinterpret_cast<bf16x8*>(d + (size_t)off * 8) = v;
}

// ---------------- binning (deterministic) ----------------

__global__ void k_bin1(const int* __restrict__ eidx, int* __restrict__ chunkhist) {
    __shared__ int h[NE];
    int t = threadIdx.x;
    if (t < NE) h[t] = 0;
    __syncthreads();
    int p = blockIdx.x * 256 + t;
    atomicAdd(&h[eidx[p]], 1);
    __syncthreads();
    if (t < NE) chunkhist[blockIdx.x * NE + t] = h[t];
}

__global__ void k_bin2(int* __restrict__ meta, const int* __restrict__ chunkhist,
                       int* __restrict__ chunkbase) {
    if (threadIdx.x == 0) {
        int counts[NE];
        for (int e = 0; e < NE; e++) counts[e] = 0;
        for (int b = 0; b < 32; b++)
            for (int e = 0; e < NE; e++) {
                chunkbase[b * NE + e] = counts[e];
                counts[e] += chunkhist[b * NE + e];
            }
        int acc = 0;
        for (int e = 0; e < NE; e++) {
            meta[e] = counts[e];      // counts
            meta[8 + e] = acc;        // exclusive offsets
            acc += counts[e];
        }
    }
}

__global__ void k_bin3(const int* __restrict__ eidx, const float* __restrict__ wts,
                       const int* __restrict__ meta, const int* __restrict__ chunkbase,
                       int* __restrict__ token_id, float* __restrict__ weightv) {
    __shared__ int earr[256];
    int t = threadIdx.x;
    int p = blockIdx.x * 256 + t;
    int e = eidx[p];
    earr[t] = e;
    __syncthreads();
    int rank = 0;
    for (int q = 0; q < t; q++) rank += (earr[q] == e) ? 1 : 0;
    int pos = meta[8 + e] + chunkbase[blockIdx.x * NE + e] + rank;
    token_id[pos] = p / TOPK;
    weightv[pos] = wts[p];
}

// ---------------- GEMM1: gu = X_e * w13[e]^T, fused SwiGLU (R7/R14 verbatim) ----------------
// Flat grid 1408 = 16 m-slots x 11 y-tiles x 8 experts. XCD-chunk swizzle:
// work = (flat%8)*176 + flat/8; grp = work>>4 in [11k, 11k+11) on XCD k.

__global__ __launch_bounds__(256, 2) void k_gemm1(
    const bf16* __restrict__ xb, const bf16* __restrict__ w13b,
    const int* __restrict__ meta, bf16* __restrict__ hact) {
    const int flat = blockIdx.x;
    const int work = (flat & 7) * 176 + (flat >> 3);
    const int mslot = work & 15;
    const int grp = work >> 4;        // [0,88)
    const int e = grp / 11;
    const int ytile = grp - e * 11;

    const int n_e = meta[e];
    const int m0 = mslot * 128;
    if (m0 >= n_e) return;
    const int base = meta[8 + e];
    const int* toks = (const int*)(meta + 64) + base;
    const bf16* wg = w13b + (size_t)e * (2 * Idim) * Hdim + (size_t)(ytile * 128) * Hdim;
    const bf16* wu = wg + (size_t)Idim * Hdim;

    __shared__ bf16 As[128 * 64];
    __shared__ bf16 Bg[128 * 64];
    __shared__ bf16 Bu[128 * 64];

    const int tid = threadIdx.x;
    const int lane = tid & 63;
    const int wid = tid >> 6;
    const int wr = wid >> 1, wc = wid & 1;
    const int l16 = lane & 15, lq = lane >> 4;

    // staging: 1024 slots of 16B per tile, 4 rounds x 256 threads.
    // LDS dest LINEAR; global source pre-swizzled: LDS seg s of row r holds
    // global seg s^(r&7).
    const bf16* gA[4];
    const bf16* gG[4];
    const bf16* gU[4];
    int lo[4];
#pragma unroll
    for (int r = 0; r < 4; r++) {
        int sid = r * 256 + tid;
        int row = sid >> 3, seg = sid & 7;
        int ss = seg ^ (row & 7);
        lo[r] = (r * 256 + (tid & ~63)) * 16;   // wave-uniform LDS byte base
        int rr = m0 + row;
        if (rr >= n_e) rr = n_e - 1;            // clamp keeps reads in-bounds
        gA[r] = xb + (size_t)toks[rr] * Hdim + ss * 8;
        gG[r] = wg + (size_t)row * Hdim + ss * 8;
        gU[r] = wu + (size_t)row * Hdim + ss * 8;
    }

    f32x4 accg[4][4], accu[4][4];
#pragma unroll
    for (int m = 0; m < 4; m++)
#pragma unroll
        for (int n = 0; n < 4; n++) {
            accg[m][n] = f32x4{0.f, 0.f, 0.f, 0.f};
            accu[m][n] = f32x4{0.f, 0.f, 0.f, 0.f};
        }

    for (int k0 = 0; k0 < Hdim; k0 += BK) {
        __syncthreads();
#pragma unroll
        for (int r = 0; r < 4; r++) {
            GLOAD16(gA[r] + k0, (char*)As + lo[r]);
            GLOAD16(gG[r] + k0, (char*)Bg + lo[r]);
            GLOAD16(gU[r] + k0, (char*)Bu + lo[r]);
        }
        __syncthreads();
#pragma unroll
        for (int kk = 0; kk < 2; ++kk) {
            bf16x8 af[4], bgf[4], buf_[4];
#pragma unroll
            for (int m = 0; m < 4; m++) {
                int row = wr * 64 + m * 16 + l16;
                int s = (kk * 4 + lq) ^ (row & 7);
                af[m] = *reinterpret_cast<const bf16x8*>(&As[row * 64 + s * 8]);
            }
#pragma unroll
            for (int n = 0; n < 4; n++) {
                int row = wc * 64 + n * 16 + l16;
                int s = (kk * 4 + lq) ^ (row & 7);
                bgf[n] = *reinterpret_cast<const bf16x8*>(&Bg[row * 64 + s * 8]);
                buf_[n] = *reinterpret_cast<const bf16x8*>(&Bu[row * 64 + s * 8]);
            }
#pragma unroll
            for (int m = 0; m < 4; m++)
#pragma unroll
                for (int n = 0; n < 4; n++) {
                    accg[m][n] = __builtin_amdgcn_mfma_f32_16x16x32_bf16(af[m], bgf[n], accg[m][n], 0, 0, 0);
                    accu[m][n] = __builtin_amdgcn_mfma_f32_16x16x32_bf16(af[m], buf_[n], accu[m][n], 0, 0, 0);
                }
        }
    }

    // epilogue: silu(g)*u -> hact. C layout: col=lane&15, row=(lane>>4)*4+reg
    const int colbase = ytile * 128 + wc * 64;
#pragma unroll
    for (int m = 0; m < 4; m++) {
        int lr0 = m0 + wr * 64 + m * 16 + lq * 4;
#pragma unroll
        for (int j = 0; j < 4; j++) {
            int lr = lr0 + j;
            if (lr < n_e) {
                size_t rowoff = (size_t)(base + lr) * Idim;
#pragma unroll
                for (int n = 0; n < 4; n++) {
                    float g = accg[m][n][j], u = accu[m][n][j];
                    float v = (g / (1.f + __expf(-g))) * u;
                    hact[rowoff + colbase + n * 16 + l16] = (bf16)v;
                }
            }
        }
    }
}

// ---------------- GEMM2: y = hact * down_proj[e]^T, weighted scatter-add ----------------
// R7/R14 verbatim 128x128. Flat grid 2048 = 16 m-slots x 16 y-tiles x 8 experts.
// XCD-chunk swizzle: work = (flat%8)*256 + flat/8 -> XCD k runs expert k.

__global__ __launch_bounds__(256, 2) void k_gemm2(
    const bf16* __restrict__ hact, const bf16* __restrict__ dpb,
    const int* __restrict__ meta, const float* __restrict__ weightv,
    float* __restrict__ out) {
    const int flat = blockIdx.x;
    const int work = (flat & 7) * 256 + (flat >> 3);
    const int mslot = work & 15;
    const int grp = work >> 4;        // [0,128)
    const int e = grp >> 4;
    const int ytile = grp & 15;

    const int n_e = meta[e];
    const int m0 = mslot * 128;
    if (m0 >= n_e) return;
    const int base = meta[8 + e];
    const int* toks = (const int*)(meta + 64) + base;
    const bf16* wb = dpb + (size_t)e * Hdim * Idim + (size_t)(ytile * 128) * Idim;

    __shared__ bf16 As[128 * 64];
    __shared__ bf16 Bs[128 * 64];

    const int tid = threadIdx.x;
    const int lane = tid & 63;
    const int wid = tid >> 6;
    const int wr = wid >> 1, wc = wid & 1;
    const int l16 = lane & 15, lq = lane >> 4;

    const bf16* gA[4];
    const bf16* gB[4];
    int lo[4];
#pragma unroll
    for (int r = 0; r < 4; r++) {
        int sid = r * 256 + tid;
        int row = sid >> 3, seg = sid & 7;
        int ss = seg ^ (row & 7);
        lo[r] = (r * 256 + (tid & ~63)) * 16;
        int rr = m0 + row;
        if (rr >= n_e) rr = n_e - 1;
        gA[r] = hact + (size_t)(base + rr) * Idim + ss * 8;
        gB[r] = wb + (size_t)row * Idim + ss * 8;
    }

    f32x4 acc[4][4];
#pragma unroll
    for (int m = 0; m < 4; m++)
#pragma unroll
        for (int n = 0; n < 4; n++) acc[m][n] = f32x4{0.f, 0.f, 0.f, 0.f};

    for (int k0 = 0; k0 < Idim; k0 += BK) {
        __syncthreads();
#pragma unroll
        for (int r = 0; r < 4; r++) {
            GLOAD16(gA[r] + k0, (char*)As + lo[r]);
            GLOAD16(gB[r] + k0, (char*)Bs + lo[r]);
        }
        __syncthreads();
#pragma unroll
        for (int kk = 0; kk < 2; ++kk) {
            bf16x8 af[4], bf_[4];
#pragma unroll
            for (int m = 0; m < 4; m++) {
                int row = wr * 64 + m * 16 + l16;
                int s = (kk * 4 + lq) ^ (row & 7);
                af[m] = *reinterpret_cast<const bf16x8*>(&As[row * 64 + s * 8]);
            }
#pragma unroll
            for (int n = 0; n < 4; n++) {
                int row = wc * 64 + n * 16 + l16;
                int s = (kk * 4 + lq) ^ (row & 7);
                bf_[n] = *reinterpret_cast<const bf16x8*>(&Bs[row * 64 + s * 8]);
            }
#pragma unroll
            for (int m = 0; m < 4; m++)
#pragma unroll
                for (int n = 0; n < 4; n++)
                    acc[m][n] = __builtin_amdgcn_mfma_f32_16x16x32_bf16(af[m], bf_[n], acc[m][n], 0, 0, 0);
        }
    }

    const int colbase = ytile * 128 + wc * 64;
#pragma unroll
    for (int m = 0; m < 4; m++) {
        int lr0 = m0 + wr * 64 + m * 16 + lq * 4;
#pragma unroll
        for (int j = 0; j < 4; j++) {
            int lr = lr0 + j;
            if (lr < n_e) {
                int tok = toks[lr];
                float w = weightv[base + lr];
#pragma unroll
                for (int n = 0; n < 4; n++) {
                    float v = acc[m][n][j] * w;
                    unsafeAtomicAdd(&out[(size_t)tok * Hdim + colbase + n * 16 + l16], v);
                }
            }
        }
    }
}

// ---------------- launch ----------------

extern "C" void kernel_launch(void* const* d_in, const int* in_sizes, int n_in,
                              void* d_out, int out_size, void* d_ws, size_t ws_size,
                              hipStream_t stream) {
    const float* x = (const float*)d_in[0];
    const int* eidx = (const int*)d_in[1];
    const float* ewts = (const float*)d_in[2];
    const float* w13 = (const float*)d_in[3];
    const float* dproj = (const float*)d_in[4];
    float* out = (float*)d_out;

    // ws layout (bytes): ints block [0, 67840), then bf16 buffers (16B-aligned)
    char* ws = (char*)d_ws;
    int* meta = (int*)ws;                       // [0..7] counts, [8..15] offsets
    int* token_id = meta + 64;                  // [NPAIR]
    float* weightv = (float*)(meta + 64 + NPAIR);
    int* chunkhist = meta + 64 + 2 * NPAIR;     // [32*NE]
    int* chunkbase = chunkhist + 256;           // [32*NE]
    bf16* xb = (bf16*)(ws + 67840);             // [NT][Hdim]
    bf16* w13b = xb + (size_t)NT * Hdim;        // [NE][2*Idim][Hdim]
    bf16* dpb = w13b + (size_t)NE * 2 * Idim * Hdim;  // [NE][Hdim][Idim]
    bf16* hact = dpb + (size_t)NE * Hdim * Idim;      // [NPAIR][Idim]

    hipMemsetAsync(d_out, 0, (size_t)out_size * sizeof(float), stream);

    k_cvt3<<<(NX8 + NW8 + ND8 + 255) / 256, 256, 0, stream>>>(x, xb, w13, w13b, dproj, dpb);

    k_bin1<<<32, 256, 0, stream>>>(eidx, chunkhist);
    k_bin2<<<1, 64, 0, stream>>>(meta, chunkhist, chunkbase);
    k_bin3<<<32, 256, 0, stream>>>(eidx, ewts, meta, chunkbase, token_id, weightv);

    k_gemm1<<<1408, 256, 0, stream>>>(xb, w13b, meta, hact);
    k_gemm2<<<2048, 256, 0, stream>>>(hact, dpb, meta, weightv, out);
}

// Round 20
// 334.237 us; speedup vs baseline: 1.0846x; 1.0454x over previous
//
#include <hip/hip_runtime.h>
#include <hip/hip_bf16.h>

// MoE SwiGLU: H=2048, I=1408, E=8, TOPK=2, T=4096 tokens (8192 pairs).
// R20 = R19 with ONE change: gemm1 N-tile halved 128->64 I-cols (g+u).
// LDS 48KB -> 32KB, acc/thread 128->64 f32 -> 5-6 blocks/CU (was ~3).
// Probes the surviving gradient of the 2-barrier family: R12/R13 showed
// bigger tiles lose (less cross-block TLP); this tests whether smaller-N
// (more blocks, +33% stage bytes) wins. gemm2/cvt3/bins = R19 verbatim.

typedef __bf16 bf16;
typedef bf16 bf16x8 __attribute__((ext_vector_type(8)));
typedef float f32x4 __attribute__((ext_vector_type(4)));

constexpr int Hdim = 2048;
constexpr int Idim = 1408;
constexpr int NE = 8;
constexpr int TOPK = 2;
constexpr int NT = 4096;      // tokens
constexpr int NPAIR = 8192;   // T * TOPK
constexpr int BK = 64;
constexpr int NX8 = NT * Hdim / 8;             // 1048576
constexpr int NW8 = NE * 2 * Idim * Hdim / 8;  // 5767168
constexpr int ND8 = NE * Hdim * Idim / 8;      // 2883584

#define GLOAD16(G, L) __builtin_amdgcn_global_load_lds(                    \
    (const __attribute__((address_space(1))) void*)(G),                    \
    (__attribute__((address_space(3))) void*)(L), 16, 0, 0)

// ---------------- f32 -> bf16 convert (all three buffers, one launch) ----------------

__global__ void k_cvt3(const float* __restrict__ x, bf16* __restrict__ xb,
                       const float* __restrict__ w13, bf16* __restrict__ w13b,
                       const float* __restrict__ dp, bf16* __restrict__ dpb) {
    int i = blockIdx.x * 256 + threadIdx.x;
    const float* s;
    bf16* d;
    int off;
    if (i < NX8) { s = x; d = xb; off = i; }
    else if (i < NX8 + NW8) { s = w13; d = w13b; off = i - NX8; }
    else if (i < NX8 + NW8 + ND8) { s = dp; d = dpb; off = i - NX8 - NW8; }
    else return;
    f32x4 a = *reinterpret_cast<const f32x4*>(s + (size_t)off * 8);
    f32x4 b = *reinterpret_cast<const f32x4*>(s + (size_t)off * 8 + 4);
    bf16x8 v;
#pragma unroll
    for (int j = 0; j < 4; j++) { v[j] = (bf16)a[j]; v[4 + j] = (bf16)b[j]; }
    *reinterpret_cast<bf16x8*>(d + (size_t)off * 8) = v;
}

// ---------------- binning (deterministic) ----------------

__global__ void k_bin1(const int* __restrict__ eidx, int* __restrict__ chunkhist) {
    __shared__ int h[NE];
    int t = threadIdx.x;
    if (t < NE) h[t] = 0;
    __syncthreads();
    int p = blockIdx.x * 256 + t;
    atomicAdd(&h[eidx[p]], 1);
    __syncthreads();
    if (t < NE) chunkhist[blockIdx.x * NE + t] = h[t];
}

__global__ void k_bin2(int* __restrict__ meta, const int* __restrict__ chunkhist,
                       int* __restrict__ chunkbase) {
    if (threadIdx.x == 0) {
        int counts[NE];
        for (int e = 0; e < NE; e++) counts[e] = 0;
        for (int b = 0; b < 32; b++)
            for (int e = 0; e < NE; e++) {
                chunkbase[b * NE + e] = counts[e];
                counts[e] += chunkhist[b * NE + e];
            }
        int acc = 0;
        for (int e = 0; e < NE; e++) {
            meta[e] = counts[e];      // counts
            meta[8 + e] = acc;        // exclusive offsets
            acc += counts[e];
        }
    }
}

__global__ void k_bin3(const int* __restrict__ eidx, const float* __restrict__ wts,
                       const int* __restrict__ meta, const int* __restrict__ chunkbase,
                       int* __restrict__ token_id, float* __restrict__ weightv) {
    __shared__ int earr[256];
    int t = threadIdx.x;
    int p = blockIdx.x * 256 + t;
    int e = eidx[p];
    earr[t] = e;
    __syncthreads();
    int rank = 0;
    for (int q = 0; q < t; q++) rank += (earr[q] == e) ? 1 : 0;
    int pos = meta[8 + e] + chunkbase[blockIdx.x * NE + e] + rank;
    token_id[pos] = p / TOPK;
    weightv[pos] = wts[p];
}

// ---------------- GEMM1: gu = X_e * w13[e]^T, fused SwiGLU ----------------
// Tile 128M x 64I (gate AND up), 256 thr = 4 waves (2M x 2N), wave 64M x 32I.
// LDS 32KB (A 16K + Bg 8K + Bu 8K) -> 5 blocks/CU. Flat grid 2816 =
// 16 m-slots x 22 y-tiles x 8 experts. XCD-chunk swizzle: work =
// (flat%8)*352 + flat/8; grp = work>>4 in [22k, 22k+22) on XCD k.

__global__ __launch_bounds__(256, 2) void k_gemm1(
    const bf16* __restrict__ xb, const bf16* __restrict__ w13b,
    const int* __restrict__ meta, bf16* __restrict__ hact) {
    const int flat = blockIdx.x;
    const int work = (flat & 7) * 352 + (flat >> 3);
    const int mslot = work & 15;
    const int grp = work >> 4;        // [0,176)
    const int e = grp / 22;
    const int ytile = grp - e * 22;   // [0,22) -> 64 I-cols each

    const int n_e = meta[e];
    const int m0 = mslot * 128;
    if (m0 >= n_e) return;
    const int base = meta[8 + e];
    const int* toks = (const int*)(meta + 64) + base;
    const bf16* wg = w13b + (size_t)e * (2 * Idim) * Hdim + (size_t)(ytile * 64) * Hdim;
    const bf16* wu = wg + (size_t)Idim * Hdim;

    __shared__ bf16 As[128 * 64];     // 16 KB
    __shared__ bf16 Bg[64 * 64];      // 8 KB
    __shared__ bf16 Bu[64 * 64];      // 8 KB

    const int tid = threadIdx.x;
    const int lane = tid & 63;
    const int wid = tid >> 6;
    const int wr = wid >> 1, wc = wid & 1;
    const int l16 = lane & 15, lq = lane >> 4;

    // staging: A = 1024 slots of 16B (4 rounds x 256 thr), Bg/Bu = 512 slots
    // (2 rounds each). LDS dest LINEAR; global seg pre-swizzled s^(row&7).
    const bf16* gA[4];
    const bf16* gG[2];
    const bf16* gU[2];
    int loA[4], loB[2];
#pragma unroll
    for (int r = 0; r < 4; r++) {
        int sid = r * 256 + tid;
        int row = sid >> 3, seg = sid & 7;
        int ss = seg ^ (row & 7);
        loA[r] = (r * 256 + (tid & ~63)) * 16;  // wave-uniform LDS byte base
        int rr = m0 + row;
        if (rr >= n_e) rr = n_e - 1;            // clamp keeps reads in-bounds
        gA[r] = xb + (size_t)toks[rr] * Hdim + ss * 8;
    }
#pragma unroll
    for (int r = 0; r < 2; r++) {
        int sid = r * 256 + tid;
        int row = sid >> 3, seg = sid & 7;      // row in [0,64)
        int ss = seg ^ (row & 7);
        loB[r] = (r * 256 + (tid & ~63)) * 16;
        gG[r] = wg + (size_t)row * Hdim + ss * 8;
        gU[r] = wu + (size_t)row * Hdim + ss * 8;
    }

    f32x4 accg[4][2], accu[4][2];
#pragma unroll
    for (int m = 0; m < 4; m++)
#pragma unroll
        for (int n = 0; n < 2; n++) {
            accg[m][n] = f32x4{0.f, 0.f, 0.f, 0.f};
            accu[m][n] = f32x4{0.f, 0.f, 0.f, 0.f};
        }

    for (int k0 = 0; k0 < Hdim; k0 += BK) {
        __syncthreads();
#pragma unroll
        for (int r = 0; r < 4; r++) GLOAD16(gA[r] + k0, (char*)As + loA[r]);
#pragma unroll
        for (int r = 0; r < 2; r++) {
            GLOAD16(gG[r] + k0, (char*)Bg + loB[r]);
            GLOAD16(gU[r] + k0, (char*)Bu + loB[r]);
        }
        __syncthreads();
#pragma unroll
        for (int kk = 0; kk < 2; ++kk) {
            bf16x8 af[4], bgf[2], buf_[2];
#pragma unroll
            for (int m = 0; m < 4; m++) {
                int row = wr * 64 + m * 16 + l16;
                int s = (kk * 4 + lq) ^ (row & 7);
                af[m] = *reinterpret_cast<const bf16x8*>(&As[row * 64 + s * 8]);
            }
#pragma unroll
            for (int n = 0; n < 2; n++) {
                int row = wc * 32 + n * 16 + l16;
                int s = (kk * 4 + lq) ^ (row & 7);
                bgf[n] = *reinterpret_cast<const bf16x8*>(&Bg[row * 64 + s * 8]);
                buf_[n] = *reinterpret_cast<const bf16x8*>(&Bu[row * 64 + s * 8]);
            }
#pragma unroll
            for (int m = 0; m < 4; m++)
#pragma unroll
                for (int n = 0; n < 2; n++) {
                    accg[m][n] = __builtin_amdgcn_mfma_f32_16x16x32_bf16(af[m], bgf[n], accg[m][n], 0, 0, 0);
                    accu[m][n] = __builtin_amdgcn_mfma_f32_16x16x32_bf16(af[m], buf_[n], accu[m][n], 0, 0, 0);
                }
        }
    }

    // epilogue: silu(g)*u -> hact. C layout: col=lane&15, row=(lane>>4)*4+reg
    const int colbase = ytile * 64 + wc * 32;
#pragma unroll
    for (int m = 0; m < 4; m++) {
        int lr0 = m0 + wr * 64 + m * 16 + lq * 4;
#pragma unroll
        for (int j = 0; j < 4; j++) {
            int lr = lr0 + j;
            if (lr < n_e) {
                size_t rowoff = (size_t)(base + lr) * Idim;
#pragma unroll
                for (int n = 0; n < 2; n++) {
                    float g = accg[m][n][j], u = accu[m][n][j];
                    float v = (g / (1.f + __expf(-g))) * u;
                    hact[rowoff + colbase + n * 16 + l16] = (bf16)v;
                }
            }
        }
    }
}

// ---------------- GEMM2: y = hact * down_proj[e]^T, weighted scatter-add ----------------
// R7/R14 verbatim 128x128. Flat grid 2048 = 16 m-slots x 16 y-tiles x 8 experts.
// XCD-chunk swizzle: work = (flat%8)*256 + flat/8 -> XCD k runs expert k.

__global__ __launch_bounds__(256, 2) void k_gemm2(
    const bf16* __restrict__ hact, const bf16* __restrict__ dpb,
    const int* __restrict__ meta, const float* __restrict__ weightv,
    float* __restrict__ out) {
    const int flat = blockIdx.x;
    const int work = (flat & 7) * 256 + (flat >> 3);
    const int mslot = work & 15;
    const int grp = work >> 4;        // [0,128)
    const int e = grp >> 4;
    const int ytile = grp & 15;

    const int n_e = meta[e];
    const int m0 = mslot * 128;
    if (m0 >= n_e) return;
    const int base = meta[8 + e];
    const int* toks = (const int*)(meta + 64) + base;
    const bf16* wb = dpb + (size_t)e * Hdim * Idim + (size_t)(ytile * 128) * Idim;

    __shared__ bf16 As[128 * 64];
    __shared__ bf16 Bs[128 * 64];

    const int tid = threadIdx.x;
    const int lane = tid & 63;
    const int wid = tid >> 6;
    const int wr = wid >> 1, wc = wid & 1;
    const int l16 = lane & 15, lq = lane >> 4;

    const bf16* gA[4];
    const bf16* gB[4];
    int lo[4];
#pragma unroll
    for (int r = 0; r < 4; r++) {
        int sid = r * 256 + tid;
        int row = sid >> 3, seg = sid & 7;
        int ss = seg ^ (row & 7);
        lo[r] = (r * 256 + (tid & ~63)) * 16;
        int rr = m0 + row;
        if (rr >= n_e) rr = n_e - 1;
        gA[r] = hact + (size_t)(base + rr) * Idim + ss * 8;
        gB[r] = wb + (size_t)row * Idim + ss * 8;
    }

    f32x4 acc[4][4];
#pragma unroll
    for (int m = 0; m < 4; m++)
#pragma unroll
        for (int n = 0; n < 4; n++) acc[m][n] = f32x4{0.f, 0.f, 0.f, 0.f};

    for (int k0 = 0; k0 < Idim; k0 += BK) {
        __syncthreads();
#pragma unroll
        for (int r = 0; r < 4; r++) {
            GLOAD16(gA[r] + k0, (char*)As + lo[r]);
            GLOAD16(gB[r] + k0, (char*)Bs + lo[r]);
        }
        __syncthreads();
#pragma unroll
        for (int kk = 0; kk < 2; ++kk) {
            bf16x8 af[4], bf_[4];
#pragma unroll
            for (int m = 0; m < 4; m++) {
                int row = wr * 64 + m * 16 + l16;
                int s = (kk * 4 + lq) ^ (row & 7);
                af[m] = *reinterpret_cast<const bf16x8*>(&As[row * 64 + s * 8]);
            }
#pragma unroll
            for (int n = 0; n < 4; n++) {
                int row = wc * 64 + n * 16 + l16;
                int s = (kk * 4 + lq) ^ (row & 7);
                bf_[n] = *reinterpret_cast<const bf16x8*>(&Bs[row * 64 + s * 8]);
            }
#pragma unroll
            for (int m = 0; m < 4; m++)
#pragma unroll
                for (int n = 0; n < 4; n++)
                    acc[m][n] = __builtin_amdgcn_mfma_f32_16x16x32_bf16(af[m], bf_[n], acc[m][n], 0, 0, 0);
        }
    }

    const int colbase = ytile * 128 + wc * 64;
#pragma unroll
    for (int m = 0; m < 4; m++) {
        int lr0 = m0 + wr * 64 + m * 16 + lq * 4;
#pragma unroll
        for (int j = 0; j < 4; j++) {
            int lr = lr0 + j;
            if (lr < n_e) {
                int tok = toks[lr];
                float w = weightv[base + lr];
#pragma unroll
                for (int n = 0; n < 4; n++) {
                    float v = acc[m][n][j] * w;
                    unsafeAtomicAdd(&out[(size_t)tok * Hdim + colbase + n * 16 + l16], v);
                }
            }
        }
    }
}

// ---------------- launch ----------------

extern "C" void kernel_launch(void* const* d_in, const int* in_sizes, int n_in,
                              void* d_out, int out_size, void* d_ws, size_t ws_size,
                              hipStream_t stream) {
    const float* x = (const float*)d_in[0];
    const int* eidx = (const int*)d_in[1];
    const float* ewts = (const float*)d_in[2];
    const float* w13 = (const float*)d_in[3];
    const float* dproj = (const float*)d_in[4];
    float* out = (float*)d_out;

    // ws layout (bytes): ints block [0, 67840), then bf16 buffers (16B-aligned)
    char* ws = (char*)d_ws;
    int* meta = (int*)ws;                       // [0..7] counts, [8..15] offsets
    int* token_id = meta + 64;                  // [NPAIR]
    float* weightv = (float*)(meta + 64 + NPAIR);
    int* chunkhist = meta + 64 + 2 * NPAIR;     // [32*NE]
    int* chunkbase = chunkhist + 256;           // [32*NE]
    bf16* xb = (bf16*)(ws + 67840);             // [NT][Hdim]
    bf16* w13b = xb + (size_t)NT * Hdim;        // [NE][2*Idim][Hdim]
    bf16* dpb = w13b + (size_t)NE * 2 * Idim * Hdim;  // [NE][Hdim][Idim]
    bf16* hact = dpb + (size_t)NE * Hdim * Idim;      // [NPAIR][Idim]

    hipMemsetAsync(d_out, 0, (size_t)out_size * sizeof(float), stream);

    k_cvt3<<<(NX8 + NW8 + ND8 + 255) / 256, 256, 0, stream>>>(x, xb, w13, w13b, dproj, dpb);

    k_bin1<<<32, 256, 0, stream>>>(eidx, chunkhist);
    k_bin2<<<1, 64, 0, stream>>>(meta, chunkhist, chunkbase);
    k_bin3<<<32, 256, 0, stream>>>(eidx, ewts, meta, chunkbase, token_id, weightv);

    k_gemm1<<<2816, 256, 0, stream>>>(xb, w13b, meta, hact);
    k_gemm2<<<2048, 256, 0, stream>>>(hact, dpb, meta, weightv, out);
}